// Round 11
// baseline (2868.912 us; speedup 1.0000x reference)
//
#include <hip/hip_runtime.h>
#include <math.h>

// Problem constants (match reference: B,N,D,L,E,NL,H = 16,1024,128,64,32,2,4)
#define Bb 16
#define Nn 1024
#define Dd 128
#define Ll 64
#define Ee 32
#define NLn 2
#define Hh 4
#define DHh 32

#define BND (Bb * Nn * Dd)
#define BLD (Bb * Ll * Dd)
#define BED (Bb * Ee * Dd)

#define SCALE_INV_SQRT_D 0.08838834764831845f /* 1/sqrt(128) */

// ---------------------------------------------------------------------------
// Encoder kernels
// ---------------------------------------------------------------------------
__global__ void enc_obs_kernel(const float* __restrict__ x, const float* __restrict__ mask,
                               const float* __restrict__ ymask, const float* __restrict__ w,
                               const float* __restrict__ bias, float* __restrict__ obs) {
    int t = blockIdx.x * 256 + threadIdx.x;
    if (t >= BND) return;
    int d = t & (Dd - 1);
    int bn = t >> 7;
    float xv = x[bn], mk = mask[bn];
    float x2 = 1.0f - mk + ymask[bn];
    float v = xv * w[d] + x2 * w[Dd + d] + bias[d];
    obs[t] = fmaxf(v, 0.0f) * mk;
}

__global__ void enc_temp_kernel(const float* __restrict__ mark, const float* __restrict__ w,
                                const float* __restrict__ bias, float* __restrict__ th) {
    int t = blockIdx.x * 256 + threadIdx.x;
    if (t >= BLD) return;
    int d = t & (Dd - 1);
    int bl = t >> 7;
    th[t] = sinf(mark[bl] * w[d] + bias[d]);
}

__global__ void enc_var_kernel(const float* __restrict__ vw, float* __restrict__ vh) {
    int t = blockIdx.x * 256 + threadIdx.x;
    if (t >= BED) return;
    int ed = t % (Ee * Dd);
    vh[t] = fmaxf(vw[ed], 0.0f);
}

// ---------------------------------------------------------------------------
// Batched GEMM, 64x128 tile, 8x4 per thread, register-staged double buffer.
// X reads in compute are wave-broadcast (2 addrs/read); LDS:VALU ~80:256 per
// k4 -> VALU-bound. Global loads for chunk ch+1 issued BEFORE computing ch.
// epi: 0 = none; 1 = resid + relu(C); 2 = relu(resid + relu(C))
// ---------------------------------------------------------------------------
__global__ __launch_bounds__(256) void gemm_kernel(
    const float* __restrict__ X0, const int* __restrict__ I0, int R0,
    const float* __restrict__ X1, const int* __restrict__ I1, int R1,
    const float* __restrict__ X2, const int* __restrict__ I2, int R2,
    const float* __restrict__ W, const float* __restrict__ bias,
    const float* __restrict__ resid, float* __restrict__ C,
    int M, int K, int epi) {
    __shared__ float Xs[2][64][36];   // 64 rows x 32 k-cols, padded
    __shared__ float Ws[2][32][132];  // 32 k-rows x 128 cols, padded

    int b = blockIdx.z;
    int row0 = blockIdx.x * 64;
    int tid = threadIdx.x;
    int tx = tid & 31, ty = tid >> 5;

    int lr = tid >> 2, cq = tid & 3;  // X staging: row lr (0..63), cols cq*8..+7
    int wc = tx * 4;                  // W staging: col group; rows ty, ty+8, ty+16, ty+24

    float acc[8][4];
#pragma unroll
    for (int r = 0; r < 8; ++r)
#pragma unroll
        for (int c = 0; c < 4; ++c) acc[r][c] = 0.0f;

    int nchunk = K >> 5;

    float4 sx0, sx1, sw0, sw1, sw2, sw3;

    auto load_ch = [&](int ch) {
        int kc = ch << 5;
        const float* Xp;
        const int* Ip;
        int Rs;
        int sel = kc >> 7;
        if (sel == 0) { Xp = X0; Ip = I0; Rs = R0; }
        else if (sel == 1) { Xp = X1; Ip = I1; Rs = R1; }
        else { Xp = X2; Ip = I2; Rs = R2; }
        int col0 = kc & (Dd - 1);
        float4 z = make_float4(0.f, 0.f, 0.f, 0.f);
        sx0 = z; sx1 = z;
        int gm = row0 + lr;
        if (gm < M) {
            int rr = Ip ? Ip[(size_t)b * M + gm] : gm;
            const float4* p = (const float4*)(Xp + ((size_t)b * Rs + rr) * Dd + col0 + cq * 8);
            sx0 = p[0];
            sx1 = p[1];
        }
        const float4* wp = (const float4*)(W + (size_t)kc * Dd + wc);
        sw0 = wp[(size_t)(ty + 0) * 32];
        sw1 = wp[(size_t)(ty + 8) * 32];
        sw2 = wp[(size_t)(ty + 16) * 32];
        sw3 = wp[(size_t)(ty + 24) * 32];
    };
    auto store_ch = [&](int buf) {
        *(float4*)&Xs[buf][lr][cq * 8] = sx0;
        *(float4*)&Xs[buf][lr][cq * 8 + 4] = sx1;
        *(float4*)&Ws[buf][ty][wc] = sw0;
        *(float4*)&Ws[buf][ty + 8][wc] = sw1;
        *(float4*)&Ws[buf][ty + 16][wc] = sw2;
        *(float4*)&Ws[buf][ty + 24][wc] = sw3;
    };

    load_ch(0);
    store_ch(0);
    __syncthreads();

    int cur = 0;
    for (int ch = 0; ch < nchunk; ++ch) {
        bool hasnext = (ch + 1) < nchunk;
        if (hasnext) load_ch(ch + 1);  // HBM latency hides under compute below

#pragma unroll
        for (int k4 = 0; k4 < 8; ++k4) {
            float4 w0 = *(const float4*)&Ws[cur][k4 * 4 + 0][tx * 4];
            float4 w1 = *(const float4*)&Ws[cur][k4 * 4 + 1][tx * 4];
            float4 w2 = *(const float4*)&Ws[cur][k4 * 4 + 2][tx * 4];
            float4 w3 = *(const float4*)&Ws[cur][k4 * 4 + 3][tx * 4];
#pragma unroll
            for (int rr = 0; rr < 8; ++rr) {
                float4 xv = *(const float4*)&Xs[cur][ty * 8 + rr][k4 * 4];  // broadcast
                acc[rr][0] += xv.x * w0.x + xv.y * w1.x + xv.z * w2.x + xv.w * w3.x;
                acc[rr][1] += xv.x * w0.y + xv.y * w1.y + xv.z * w2.y + xv.w * w3.y;
                acc[rr][2] += xv.x * w0.z + xv.y * w1.z + xv.z * w2.z + xv.w * w3.z;
                acc[rr][3] += xv.x * w0.w + xv.y * w1.w + xv.z * w2.w + xv.w * w3.w;
            }
        }

        if (hasnext) {
            __syncthreads();       // everyone done reading buf cur (and cur^1 long ago)
            store_ch(cur ^ 1);
            __syncthreads();       // writes visible before next compute
            cur ^= 1;
        }
    }

    float4 bv = *(const float4*)&bias[tx * 4];
#pragma unroll
    for (int rr = 0; rr < 8; ++rr) {
        int gm = row0 + ty * 8 + rr;
        if (gm >= M) continue;
        size_t base = ((size_t)b * M + gm) * Dd + tx * 4;
        float4 o;
        o.x = acc[rr][0] + bv.x;
        o.y = acc[rr][1] + bv.y;
        o.z = acc[rr][2] + bv.z;
        o.w = acc[rr][3] + bv.w;
        if (epi >= 1) {
            float4 r4 = *(const float4*)&resid[base];
            o.x = r4.x + fmaxf(o.x, 0.f);
            o.y = r4.y + fmaxf(o.y, 0.f);
            o.z = r4.z + fmaxf(o.z, 0.f);
            o.w = r4.w + fmaxf(o.w, 0.f);
            if (epi == 2) {
                o.x = fmaxf(o.x, 0.f);
                o.y = fmaxf(o.y, 0.f);
                o.z = fmaxf(o.z, 0.f);
                o.w = fmaxf(o.w, 0.f);
            }
        }
        *(float4*)&C[base] = o;
    }
}

// ---------------------------------------------------------------------------
// Incidence-masked flash attention (temporal/var): proven round-6 kernel.
// ---------------------------------------------------------------------------
__global__ __launch_bounds__(256, 2) void attn_inc_kernel(
    const float* __restrict__ Q, const float* __restrict__ Kp, const float* __restrict__ Vp,
    const int* __restrict__ idxp, const float* __restrict__ maskp,
    float* __restrict__ O, int M) {
    __shared__ float Kt[32][65];
    __shared__ float Vt[32][65];
    __shared__ float Qs[32][36];
    __shared__ float Ps[4][64];

    int b = blockIdx.z, h = blockIdx.y;
    int tid = threadIdx.x;
    int lane = tid & 63, wid = tid >> 6;
    int mblk = blockIdx.x * 32;
    int m0 = mblk + wid * 8;

    int kh = lane >> 5;
    int dv = lane & 31;

    {
        int r = tid >> 3, c = tid & 7;
        float4 qv = *(const float4*)(Q + ((size_t)b * M + mblk + r) * Dd + (size_t)h * DHh + c * 4);
        *(float4*)&Qs[r][c * 4] = qv;
    }

    float acc[8], lpart[8], mrun[8];
#pragma unroll
    for (int qi = 0; qi < 8; ++qi) { acc[qi] = 0.f; lpart[qi] = 0.f; mrun[qi] = -INFINITY; }

    for (int n0 = 0; n0 < Nn; n0 += 64) {
        __syncthreads();
        {
            int k = tid >> 2, q4 = tid & 3;
            size_t gk = ((size_t)b * Nn + n0 + k) * Dd + (size_t)h * DHh;
            const float4* kp = (const float4*)(Kp + gk) + q4 * 2;
            const float4* vp = (const float4*)(Vp + gk) + q4 * 2;
            float4 k0 = kp[0], k1 = kp[1];
            float4 v0 = vp[0], v1 = vp[1];
            int d0 = q4 * 8;
            Kt[d0 + 0][k] = k0.x; Kt[d0 + 1][k] = k0.y; Kt[d0 + 2][k] = k0.z; Kt[d0 + 3][k] = k0.w;
            Kt[d0 + 4][k] = k1.x; Kt[d0 + 5][k] = k1.y; Kt[d0 + 6][k] = k1.z; Kt[d0 + 7][k] = k1.w;
            Vt[d0 + 0][k] = v0.x; Vt[d0 + 1][k] = v0.y; Vt[d0 + 2][k] = v0.z; Vt[d0 + 3][k] = v0.w;
            Vt[d0 + 4][k] = v1.x; Vt[d0 + 5][k] = v1.y; Vt[d0 + 6][k] = v1.z; Vt[d0 + 7][k] = v1.w;
        }
        float km = maskp[(size_t)b * Nn + n0 + lane];
        bool kok = (km != 0.0f);
        int tag = idxp[(size_t)b * Nn + n0 + lane];
        __syncthreads();

        bool anyUse = __any(kok && (unsigned)(tag - m0) < 8u);
        float minm = fminf(fminf(fminf(mrun[0], mrun[1]), fminf(mrun[2], mrun[3])),
                           fminf(fminf(mrun[4], mrun[5]), fminf(mrun[6], mrun[7])));
        if (!anyUse && minm > -5e9f) continue;

        float kreg[32], vreg[32];
#pragma unroll
        for (int j = 0; j < 32; ++j) kreg[j] = Kt[j][lane];
#pragma unroll
        for (int j = 0; j < 32; ++j) vreg[j] = Vt[dv][kh * 32 + j];

#pragma unroll
        for (int qi = 0; qi < 8; ++qi) {
            bool ok = kok && (tag == m0 + qi);
            if (!__any(ok) && mrun[qi] > -5e9f) continue;

            const float4* qrow = (const float4*)&Qs[wid * 8 + qi][0];
            float s0 = 0.f, s1 = 0.f, s2 = 0.f, s3 = 0.f;
#pragma unroll
            for (int j4 = 0; j4 < 8; ++j4) {
                float4 qv = qrow[j4];
                s0 += qv.x * kreg[j4 * 4 + 0];
                s1 += qv.y * kreg[j4 * 4 + 1];
                s2 += qv.z * kreg[j4 * 4 + 2];
                s3 += qv.w * kreg[j4 * 4 + 3];
            }
            float s = (s0 + s1) + (s2 + s3);
            s = ok ? s * SCALE_INV_SQRT_D : -1e10f;

            float cmax = s;
#pragma unroll
            for (int off = 32; off >= 1; off >>= 1)
                cmax = fmaxf(cmax, __shfl_xor(cmax, off, 64));

            if (cmax > mrun[qi]) {
                float corr = __expf(mrun[qi] - cmax);
                lpart[qi] *= corr;
                acc[qi] *= corr;
                mrun[qi] = cmax;
            }
            float p = __expf(s - mrun[qi]);
            lpart[qi] += p;
            Ps[wid][lane] = p;

            float a = acc[qi];
#pragma unroll
            for (int j4 = 0; j4 < 8; ++j4) {
                float4 pv = *(const float4*)&Ps[wid][kh * 32 + j4 * 4];
                a += pv.x * vreg[j4 * 4 + 0];
                a += pv.y * vreg[j4 * 4 + 1];
                a += pv.z * vreg[j4 * 4 + 2];
                a += pv.w * vreg[j4 * 4 + 3];
            }
            acc[qi] = a;
        }
    }

#pragma unroll
    for (int qi = 0; qi < 8; ++qi) {
        float l = lpart[qi];
#pragma unroll
        for (int off = 32; off >= 1; off >>= 1) l += __shfl_xor(l, off, 64);
        float a = acc[qi] + __shfl_xor(acc[qi], 32, 64);
        float inv = 1.0f / l;
        if (lane < 32) {
            int r = wid * 8 + qi;
            float qd = Qs[r][lane];
            O[((size_t)b * M + mblk + r) * Dd + (size_t)h * DHh + lane] = qd + a * inv;
        }
    }
}

// ---------------------------------------------------------------------------
// Obs (nmask) flash attention, KVBLK=128, spill-free two-pass S phase:
// pass A fills kreg[32] for keys n0+lane -> sa[8]; pass B reuses kreg for
// keys n0+64+lane -> sb[8] (kreg dead before vreg[64] is filled; peak live
// ~110 VGPR). One butterfly/exp/rescale per 128 keys (round-10 amortization).
// ---------------------------------------------------------------------------
__global__ __launch_bounds__(256, 2) void attn_obs_kernel(
    const float* __restrict__ Q, const float* __restrict__ Kp, const float* __restrict__ Vp,
    const float* __restrict__ maskp, float* __restrict__ O) {
    __shared__ float Kt[32][129];  // Kt[d][k], k = 0..127
    __shared__ float Vt[32][129];
    __shared__ float Qs[32][36];
    __shared__ float Ps[4][128];

    int b = blockIdx.z, h = blockIdx.y;
    int tid = threadIdx.x;
    int lane = tid & 63, wid = tid >> 6;
    int mblk = blockIdx.x * 32;
    int m0 = mblk + wid * 8;

    int kh = lane >> 5;
    int dv = lane & 31;

    {
        int r = tid >> 3, c = tid & 7;
        float4 qv = *(const float4*)(Q + ((size_t)b * Nn + mblk + r) * Dd + (size_t)h * DHh + c * 4);
        *(float4*)&Qs[r][c * 4] = qv;
    }

    float acc[8], lpart[8], mrun[8];
    bool okq[8];
#pragma unroll
    for (int qi = 0; qi < 8; ++qi) {
        acc[qi] = 0.f; lpart[qi] = 0.f; mrun[qi] = -INFINITY;
        okq[qi] = (maskp[(size_t)b * Nn + m0 + qi] != 0.0f);
    }

    for (int n0 = 0; n0 < Nn; n0 += 128) {
        __syncthreads();
        {   // stage K/V transposed: key k = tid>>1, dim-half hf = tid&1
            int k = tid >> 1, hf = tid & 1;
            size_t gk = ((size_t)b * Nn + n0 + k) * Dd + (size_t)h * DHh + hf * 16;
            const float4* kp = (const float4*)(Kp + gk);
            const float4* vp = (const float4*)(Vp + gk);
#pragma unroll
            for (int q4 = 0; q4 < 4; ++q4) {
                float4 kv = kp[q4];
                float4 vv = vp[q4];
                int d0 = hf * 16 + q4 * 4;
                Kt[d0 + 0][k] = kv.x; Kt[d0 + 1][k] = kv.y;
                Kt[d0 + 2][k] = kv.z; Kt[d0 + 3][k] = kv.w;
                Vt[d0 + 0][k] = vv.x; Vt[d0 + 1][k] = vv.y;
                Vt[d0 + 2][k] = vv.z; Vt[d0 + 3][k] = vv.w;
            }
        }
        bool kok_a = (maskp[(size_t)b * Nn + n0 + lane] != 0.0f);
        bool kok_b = (maskp[(size_t)b * Nn + n0 + 64 + lane] != 0.0f);
        __syncthreads();

        float sa[8], sb[8];
        {   // ---- S pass A: keys n0+lane ----
            float kreg[32];
#pragma unroll
            for (int j = 0; j < 32; ++j) kreg[j] = Kt[j][lane];
#pragma unroll
            for (int qi = 0; qi < 8; ++qi) {
                const float4* qrow = (const float4*)&Qs[wid * 8 + qi][0];
                float t0 = 0.f, t1 = 0.f, t2 = 0.f, t3 = 0.f;
#pragma unroll
                for (int j4 = 0; j4 < 8; ++j4) {
                    float4 qv = qrow[j4];
                    t0 += qv.x * kreg[j4 * 4 + 0];
                    t1 += qv.y * kreg[j4 * 4 + 1];
                    t2 += qv.z * kreg[j4 * 4 + 2];
                    t3 += qv.w * kreg[j4 * 4 + 3];
                }
                sa[qi] = (t0 + t1) + (t2 + t3);
            }
        }
        {   // ---- S pass B: keys n0+64+lane (kreg registers reused) ----
            float kreg[32];
#pragma unroll
            for (int j = 0; j < 32; ++j) kreg[j] = Kt[j][64 + lane];
#pragma unroll
            for (int qi = 0; qi < 8; ++qi) {
                const float4* qrow = (const float4*)&Qs[wid * 8 + qi][0];
                float t0 = 0.f, t1 = 0.f, t2 = 0.f, t3 = 0.f;
#pragma unroll
                for (int j4 = 0; j4 < 8; ++j4) {
                    float4 qv = qrow[j4];
                    t0 += qv.x * kreg[j4 * 4 + 0];
                    t1 += qv.y * kreg[j4 * 4 + 1];
                    t2 += qv.z * kreg[j4 * 4 + 2];
                    t3 += qv.w * kreg[j4 * 4 + 3];
                }
                sb[qi] = (t0 + t1) + (t2 + t3);
            }
        }
#pragma unroll
        for (int qi = 0; qi < 8; ++qi) {
            sa[qi] = (okq[qi] && kok_a) ? sa[qi] * SCALE_INV_SQRT_D : -1e10f;
            sb[qi] = (okq[qi] && kok_b) ? sb[qi] * SCALE_INV_SQRT_D : -1e10f;
        }

        // vreg fill (after kreg is dead)
        float vreg[64];
#pragma unroll
        for (int j = 0; j < 32; ++j) {
            vreg[j] = Vt[dv][kh * 32 + j];
            vreg[32 + j] = Vt[dv][64 + kh * 32 + j];
        }

#pragma unroll
        for (int qi = 0; qi < 8; ++qi) {
            float cmax = fmaxf(sa[qi], sb[qi]);
#pragma unroll
            for (int off = 32; off >= 1; off >>= 1)
                cmax = fmaxf(cmax, __shfl_xor(cmax, off, 64));

            float nm = fmaxf(mrun[qi], cmax);
            float corr = __expf(mrun[qi] - nm);  // exp(-inf)=0 on first chunk
            mrun[qi] = nm;
            float pa = __expf(sa[qi] - nm);
            float pb = __expf(sb[qi] - nm);
            lpart[qi] = lpart[qi] * corr + pa + pb;
            acc[qi] *= corr;
            Ps[wid][lane] = pa;
            Ps[wid][64 + lane] = pb;

            float a = acc[qi];
#pragma unroll
            for (int j4 = 0; j4 < 8; ++j4) {
                float4 pv = *(const float4*)&Ps[wid][kh * 32 + j4 * 4];
                a += pv.x * vreg[j4 * 4 + 0];
                a += pv.y * vreg[j4 * 4 + 1];
                a += pv.z * vreg[j4 * 4 + 2];
                a += pv.w * vreg[j4 * 4 + 3];
            }
#pragma unroll
            for (int j4 = 0; j4 < 8; ++j4) {
                float4 pv = *(const float4*)&Ps[wid][64 + kh * 32 + j4 * 4];
                a += pv.x * vreg[32 + j4 * 4 + 0];
                a += pv.y * vreg[32 + j4 * 4 + 1];
                a += pv.z * vreg[32 + j4 * 4 + 2];
                a += pv.w * vreg[32 + j4 * 4 + 3];
            }
            acc[qi] = a;
        }
    }

#pragma unroll
    for (int qi = 0; qi < 8; ++qi) {
        float l = lpart[qi];
#pragma unroll
        for (int off = 32; off >= 1; off >>= 1) l += __shfl_xor(l, off, 64);
        float a = acc[qi] + __shfl_xor(acc[qi], 32, 64);
        float inv = 1.0f / l;
        if (lane < 32) {
            int r = wid * 8 + qi;
            float qd = Qs[r][lane];
            O[((size_t)b * Nn + mblk + r) * Dd + (size_t)h * DHh + lane] = qd + a * inv;
        }
    }
}

// ---------------------------------------------------------------------------
// IAA (hyperedge2hyperedge): tiny single-head attention over E=32.
// ---------------------------------------------------------------------------
__global__ void iaa_scores_kernel(const float* __restrict__ q, const float* __restrict__ k,
                                  float* __restrict__ s) {
    int t = blockIdx.x * 256 + threadIdx.x;
    if (t >= Bb * Ee * Ee) return;
    int j = t & (Ee - 1);
    int i = (t >> 5) & (Ee - 1);
    int b = t >> 10;
    const float4* qp = (const float4*)(q + ((size_t)b * Ee + i) * Dd);
    const float4* kp = (const float4*)(k + ((size_t)b * Ee + j) * Dd);
    float acc = 0.0f;
#pragma unroll
    for (int d = 0; d < 32; ++d) {
        float4 a = qp[d], c = kp[d];
        acc += a.x * c.x + a.y * c.y + a.z * c.z + a.w * c.w;
    }
    s[t] = acc * SCALE_INV_SQRT_D;
}

__global__ void iaa_softmax_kernel(float* __restrict__ s) {
    int r = blockIdx.x * 256 + threadIdx.x;
    if (r >= Bb * Ee) return;
    float* row = s + (size_t)r * Ee;
    float mx = -INFINITY;
    for (int j = 0; j < Ee; ++j) mx = fmaxf(mx, row[j]);
    float sum = 0.0f;
    for (int j = 0; j < Ee; ++j) sum += __expf(row[j] - mx);
    float inv = 1.0f / sum;
    for (int j = 0; j < Ee; ++j) row[j] = __expf(row[j] - mx) * inv;
}

__global__ void iaa_av_kernel(const float* __restrict__ s, const float* __restrict__ v,
                              float* __restrict__ o) {
    int t = blockIdx.x * 256 + threadIdx.x;
    if (t >= Bb * Ee * Dd) return;
    int d = t & (Dd - 1);
    int i = (t >> 7) & (Ee - 1);
    int b = t >> 12;
    const float* sr = s + ((size_t)b * Ee + i) * Ee;
    float acc = 0.0f;
#pragma unroll
    for (int j = 0; j < Ee; ++j) acc += sr[j] * v[((size_t)b * Ee + j) * Dd + d];
    o[t] = acc;
}

// ---------------------------------------------------------------------------
// Host-side orchestration
// ---------------------------------------------------------------------------
static inline void launch_gemm(hipStream_t st, const float* X0, const int* I0, int R0,
                               const float* X1, const int* I1, int R1, const float* X2,
                               const int* I2, int R2, const float* W, const float* bias,
                               const float* resid, float* C, int M, int K, int epi) {
    dim3 g((M + 63) / 64, 1, Bb);
    gemm_kernel<<<g, 256, 0, st>>>(X0, I0, R0, X1, I1, R1, X2, I2, R2, W, bias, resid, C, M, K,
                                   epi);
}

static inline void launch_attn_inc(hipStream_t st, const float* Q, const float* K, const float* V,
                                   const int* idxp, const float* maskp, float* O, int M) {
    dim3 g(M / 32, Hh, Bb);
    attn_inc_kernel<<<g, 256, 0, st>>>(Q, K, V, idxp, maskp, O, M);
}

static inline void launch_attn_obs(hipStream_t st, const float* Q, const float* K, const float* V,
                                   const float* maskp, float* O) {
    dim3 g(Nn / 32, Hh, Bb);
    attn_obs_kernel<<<g, 256, 0, st>>>(Q, K, V, maskp, O);
}

extern "C" void kernel_launch(void* const* d_in, const int* in_sizes, int n_in, void* d_out,
                              int out_size, void* d_ws, size_t ws_size, hipStream_t stream) {
    const float* x = (const float*)d_in[0];
    const float* mask = (const float*)d_in[1];
    const float* ymask = (const float*)d_in[2];
    const float* mark = (const float*)d_in[3];
    const float* w_obs = (const float*)d_in[4];
    const float* b_obs = (const float*)d_in[5];
    const float* w_tm = (const float*)d_in[6];
    const float* b_tm = (const float*)d_in[7];
    const float* var_w = (const float*)d_in[8];
    const float* tq_w = (const float*)d_in[9];
    const float* tq_b = (const float*)d_in[10];
    const float* tk_w = (const float*)d_in[11];
    const float* tk_b = (const float*)d_in[12];
    const float* tv_w = (const float*)d_in[13];
    const float* tv_b = (const float*)d_in[14];
    const float* to_w = (const float*)d_in[15];
    const float* to_b = (const float*)d_in[16];
    const float* vq_w = (const float*)d_in[17];
    const float* vq_b = (const float*)d_in[18];
    const float* vk_w = (const float*)d_in[19];
    const float* vk_b = (const float*)d_in[20];
    const float* vv_w = (const float*)d_in[21];
    const float* vv_b = (const float*)d_in[22];
    const float* vo_w = (const float*)d_in[23];
    const float* vo_b = (const float*)d_in[24];
    const float* sq_w = (const float*)d_in[25];
    const float* sq_b = (const float*)d_in[26];
    const float* sk_w = (const float*)d_in[27];
    const float* sk_b = (const float*)d_in[28];
    const float* sv_w = (const float*)d_in[29];
    const float* sv_b = (const float*)d_in[30];
    const float* so_w = (const float*)d_in[31];
    const float* so_b = (const float*)d_in[32];
    const float* iq_w = (const float*)d_in[33];
    const float* iq_b = (const float*)d_in[34];
    const float* ik_w = (const float*)d_in[35];
    const float* ik_b = (const float*)d_in[36];
    const float* iv_w = (const float*)d_in[37];
    const float* iv_b = (const float*)d_in[38];
    const int* vidx = (const int*)d_in[39];
    const int* tidx = (const int*)d_in[40];

    float* out = (float*)d_out;
    float* out_obs = out;
    float* out_temp = out + BND;
    float* out_var = out + BND + BLD;

    float* ws = (float*)d_ws;
    float* obs_a = ws;
    float* obs_b = obs_a + BND;
    float* qb = obs_b + BND;
    float* kb = qb + BND;
    float* vb = kb + BND;
    float* attno = vb + BND;
    float* temp_a = attno + BND;
    float* temp_b = temp_a + BLD;
    float* var_a = temp_b + BLD;
    float* var_b = var_a + BED;
    float* sbuf = var_b + BED;  // B*E*E

    enc_obs_kernel<<<(BND + 255) / 256, 256, 0, stream>>>(x, mask, ymask, w_obs, b_obs, obs_a);
    enc_temp_kernel<<<(BLD + 255) / 256, 256, 0, stream>>>(mark, w_tm, b_tm, temp_a);
    enc_var_kernel<<<(BED + 255) / 256, 256, 0, stream>>>(var_w, var_a);

    float* t_old = temp_a;
    float* v_old = var_a;
    float* o_old = obs_a;

    for (int i = 0; i < NLn; ++i) {
        int last = (i == NLn - 1);
        float* t_new = last ? out_temp : temp_b;
        float* v_new = (v_old == var_a) ? var_b : var_a;
        float* o_new = last ? out_obs : obs_b;

        const float* tqW = tq_w + (size_t)i * Dd * Dd;
        const float* tkW = tk_w + (size_t)i * 2 * Dd * Dd;
        const float* tvW = tv_w + (size_t)i * 2 * Dd * Dd;
        const float* toW = to_w + (size_t)i * Dd * Dd;
        const float* vqW = vq_w + (size_t)i * Dd * Dd;
        const float* vkW = vk_w + (size_t)i * 2 * Dd * Dd;
        const float* vvW = vv_w + (size_t)i * 2 * Dd * Dd;
        const float* voW = vo_w + (size_t)i * Dd * Dd;
        const float* sqW = sq_w + (size_t)i * Dd * Dd;
        const float* skW = sk_w + (size_t)i * 3 * Dd * Dd;
        const float* svW = sv_w + (size_t)i * 3 * Dd * Dd;
        const float* soW = so_w + (size_t)i * Dd * Dd;

        // ---- temporal MAB: Q=temp_he(old), K=[var_g(old), obs] ----
        launch_gemm(stream, t_old, nullptr, Ll, nullptr, nullptr, 0, nullptr, nullptr, 0, tqW,
                    tq_b + i * Dd, nullptr, qb, Ll, Dd, 0);
        launch_gemm(stream, v_old, vidx, Ee, o_old, nullptr, Nn, nullptr, nullptr, 0, tkW,
                    tk_b + i * Dd, nullptr, kb, Nn, 2 * Dd, 0);
        launch_gemm(stream, v_old, vidx, Ee, o_old, nullptr, Nn, nullptr, nullptr, 0, tvW,
                    tv_b + i * Dd, nullptr, vb, Nn, 2 * Dd, 0);
        launch_attn_inc(stream, qb, kb, vb, tidx, mask, attno, Ll);
        launch_gemm(stream, attno, nullptr, Ll, nullptr, nullptr, 0, nullptr, nullptr, 0, toW,
                    to_b + i * Dd, attno, t_new, Ll, Dd, 1);

        // ---- variable MAB: Q=var_he(old), K=[temp_g(old), obs] ----
        launch_gemm(stream, v_old, nullptr, Ee, nullptr, nullptr, 0, nullptr, nullptr, 0, vqW,
                    vq_b + i * Dd, nullptr, qb, Ee, Dd, 0);
        launch_gemm(stream, t_old, tidx, Ll, o_old, nullptr, Nn, nullptr, nullptr, 0, vkW,
                    vk_b + i * Dd, nullptr, kb, Nn, 2 * Dd, 0);
        launch_gemm(stream, t_old, tidx, Ll, o_old, nullptr, Nn, nullptr, nullptr, 0, vvW,
                    vv_b + i * Dd, nullptr, vb, Nn, 2 * Dd, 0);
        launch_attn_inc(stream, qb, kb, vb, vidx, mask, attno, Ee);
        launch_gemm(stream, attno, nullptr, Ee, nullptr, nullptr, 0, nullptr, nullptr, 0, voW,
                    vo_b + i * Dd, attno, v_new, Ee, Dd, 1);

        // ---- obs MAB: Q=obs(old), K=[temp_g(new), var_g(new), obs(old)] ----
        launch_gemm(stream, o_old, nullptr, Nn, nullptr, nullptr, 0, nullptr, nullptr, 0, sqW,
                    sq_b + i * Dd, nullptr, qb, Nn, Dd, 0);
        launch_gemm(stream, t_new, tidx, Ll, v_new, vidx, Ee, o_old, nullptr, Nn, skW,
                    sk_b + i * Dd, nullptr, kb, Nn, 3 * Dd, 0);
        launch_gemm(stream, t_new, tidx, Ll, v_new, vidx, Ee, o_old, nullptr, Nn, svW,
                    sv_b + i * Dd, nullptr, vb, Nn, 3 * Dd, 0);
        launch_attn_obs(stream, qb, kb, vb, mask, attno);
        launch_gemm(stream, attno, nullptr, Nn, nullptr, nullptr, 0, nullptr, nullptr, 0, soW,
                    so_b + i * Dd, attno, o_new, Nn, Dd, 2);

        t_old = t_new;
        v_old = v_new;
        o_old = o_new;
    }

    // ---- IAA on var_he (last layer) ----
    launch_gemm(stream, v_old, nullptr, Ee, nullptr, nullptr, 0, nullptr, nullptr, 0, iq_w, iq_b,
                nullptr, qb, Ee, Dd, 0);
    launch_gemm(stream, v_old, nullptr, Ee, nullptr, nullptr, 0, nullptr, nullptr, 0, ik_w, ik_b,
                nullptr, kb, Ee, Dd, 0);
    launch_gemm(stream, v_old, nullptr, Ee, nullptr, nullptr, 0, nullptr, nullptr, 0, iv_w, iv_b,
                nullptr, vb, Ee, Dd, 0);
    iaa_scores_kernel<<<(Bb * Ee * Ee + 255) / 256, 256, 0, stream>>>(qb, kb, sbuf);
    iaa_softmax_kernel<<<(Bb * Ee + 255) / 256, 256, 0, stream>>>(sbuf);
    iaa_av_kernel<<<(Bb * Ee * Dd + 255) / 256, 256, 0, stream>>>(sbuf, vb, out_var);
}

// Round 12
// 1305.033 us; speedup vs baseline: 2.1983x; 2.1983x over previous
//
#include <hip/hip_runtime.h>
#include <math.h>

// Problem constants (match reference: B,N,D,L,E,NL,H = 16,1024,128,64,32,2,4)
#define Bb 16
#define Nn 1024
#define Dd 128
#define Ll 64
#define Ee 32
#define NLn 2
#define Hh 4
#define DHh 32

#define BND (Bb * Nn * Dd)
#define BLD (Bb * Ll * Dd)
#define BED (Bb * Ee * Dd)

#define SCALE_INV_SQRT_D 0.08838834764831845f /* 1/sqrt(128) */

typedef float f32x4 __attribute__((ext_vector_type(4)));
typedef short bf16x8 __attribute__((ext_vector_type(8)));

__device__ inline short f2bf(float f) {  // RNE f32 -> bf16
    unsigned u = __float_as_uint(f);
    u += 0x7fffu + ((u >> 16) & 1u);
    return (short)(u >> 16);
}
__device__ inline float bf2f(short s) {
    return __uint_as_float(((unsigned)(unsigned short)s) << 16);
}
// split f32 into hi (bf16) + lo (bf16 of residual): a*b via 3 MFMAs ~ fp32 acc.
__device__ inline void split8(const float* v, bf16x8& hi, bf16x8& lo) {
#pragma unroll
    for (int j = 0; j < 8; ++j) {
        short h = f2bf(v[j]);
        hi[j] = h;
        lo[j] = f2bf(v[j] - bf2f(h));
    }
}

// ---------------------------------------------------------------------------
// Encoder kernels
// ---------------------------------------------------------------------------
__global__ void enc_obs_kernel(const float* __restrict__ x, const float* __restrict__ mask,
                               const float* __restrict__ ymask, const float* __restrict__ w,
                               const float* __restrict__ bias, float* __restrict__ obs) {
    int t = blockIdx.x * 256 + threadIdx.x;
    if (t >= BND) return;
    int d = t & (Dd - 1);
    int bn = t >> 7;
    float xv = x[bn], mk = mask[bn];
    float x2 = 1.0f - mk + ymask[bn];
    float v = xv * w[d] + x2 * w[Dd + d] + bias[d];
    obs[t] = fmaxf(v, 0.0f) * mk;
}

__global__ void enc_temp_kernel(const float* __restrict__ mark, const float* __restrict__ w,
                                const float* __restrict__ bias, float* __restrict__ th) {
    int t = blockIdx.x * 256 + threadIdx.x;
    if (t >= BLD) return;
    int d = t & (Dd - 1);
    int bl = t >> 7;
    th[t] = sinf(mark[bl] * w[d] + bias[d]);
}

__global__ void enc_var_kernel(const float* __restrict__ vw, float* __restrict__ vh) {
    int t = blockIdx.x * 256 + threadIdx.x;
    if (t >= BED) return;
    int ed = t % (Ee * Dd);
    vh[t] = fmaxf(vw[ed], 0.0f);
}

// ---------------------------------------------------------------------------
// Generic batched GEMM (round-6 proven): 32-row tiles.
// epi: 0 = none; 1 = resid + relu(C); 2 = relu(resid + relu(C))
// ---------------------------------------------------------------------------
__global__ __launch_bounds__(256) void gemm_kernel(
    const float* __restrict__ X0, const int* __restrict__ I0, int R0,
    const float* __restrict__ X1, const int* __restrict__ I1, int R1,
    const float* __restrict__ X2, const int* __restrict__ I2, int R2,
    const float* __restrict__ W, const float* __restrict__ bias,
    const float* __restrict__ resid, float* __restrict__ C,
    int M, int K, int epi) {
    __shared__ float Xs[32][36];
    __shared__ float Ws[32][132];

    int b = blockIdx.z;
    int row0 = blockIdx.x * 32;
    int tid = threadIdx.x;
    int tx = tid & 31, ty = tid >> 5;

    float acc[4][4];
#pragma unroll
    for (int r = 0; r < 4; ++r)
#pragma unroll
        for (int c = 0; c < 4; ++c) acc[r][c] = 0.0f;

    int nchunk = K >> 5;
    for (int ch = 0; ch < nchunk; ++ch) {
        int kc = ch << 5;
        const float* Xp;
        const int* Ip;
        int Rs;
        int sel = kc >> 7;
        if (sel == 0) { Xp = X0; Ip = I0; Rs = R0; }
        else if (sel == 1) { Xp = X1; Ip = I1; Rs = R1; }
        else { Xp = X2; Ip = I2; Rs = R2; }
        int col0 = kc & (Dd - 1);

        __syncthreads();
        {
            int lr = tid >> 3, cq = tid & 7;
            int gm = row0 + lr;
            float4 a0 = make_float4(0.f, 0.f, 0.f, 0.f);
            if (gm < M) {
                int rr = Ip ? Ip[(size_t)b * M + gm] : gm;
                a0 = *(const float4*)(Xp + ((size_t)b * Rs + rr) * Dd + col0 + cq * 4);
            }
            *(float4*)&Xs[lr][cq * 4] = a0;
        }
        {
            int kr = tid >> 5, c = (tid & 31) * 4;
#pragma unroll
            for (int i = 0; i < 4; ++i) {
                int krow = kr + i * 8;
                *(float4*)&Ws[krow][c] = *(const float4*)&W[(size_t)(kc + krow) * Dd + c];
            }
        }
        __syncthreads();

#pragma unroll
        for (int k4 = 0; k4 < 8; ++k4) {
            float4 w0 = *(const float4*)&Ws[k4 * 4 + 0][tx * 4];
            float4 w1 = *(const float4*)&Ws[k4 * 4 + 1][tx * 4];
            float4 w2 = *(const float4*)&Ws[k4 * 4 + 2][tx * 4];
            float4 w3 = *(const float4*)&Ws[k4 * 4 + 3][tx * 4];
#pragma unroll
            for (int rr = 0; rr < 4; ++rr) {
                float4 xv = *(const float4*)&Xs[ty * 4 + rr][k4 * 4];
                acc[rr][0] += xv.x * w0.x + xv.y * w1.x + xv.z * w2.x + xv.w * w3.x;
                acc[rr][1] += xv.x * w0.y + xv.y * w1.y + xv.z * w2.y + xv.w * w3.y;
                acc[rr][2] += xv.x * w0.z + xv.y * w1.z + xv.z * w2.z + xv.w * w3.z;
                acc[rr][3] += xv.x * w0.w + xv.y * w1.w + xv.z * w2.w + xv.w * w3.w;
            }
        }
    }

    float4 bv = *(const float4*)&bias[tx * 4];
#pragma unroll
    for (int rr = 0; rr < 4; ++rr) {
        int gm = row0 + ty * 4 + rr;
        if (gm >= M) continue;
        size_t base = ((size_t)b * M + gm) * Dd + tx * 4;
        float4 o;
        o.x = acc[rr][0] + bv.x;
        o.y = acc[rr][1] + bv.y;
        o.z = acc[rr][2] + bv.z;
        o.w = acc[rr][3] + bv.w;
        if (epi >= 1) {
            float4 r4 = *(const float4*)&resid[base];
            o.x = r4.x + fmaxf(o.x, 0.f);
            o.y = r4.y + fmaxf(o.y, 0.f);
            o.z = r4.z + fmaxf(o.z, 0.f);
            o.w = r4.w + fmaxf(o.w, 0.f);
            if (epi == 2) {
                o.x = fmaxf(o.x, 0.f);
                o.y = fmaxf(o.y, 0.f);
                o.z = fmaxf(o.z, 0.f);
                o.w = fmaxf(o.w, 0.f);
            }
        }
        *(float4*)&C[base] = o;
    }
}

// ---------------------------------------------------------------------------
// Incidence-masked flash attention (temporal/var): proven round-6 kernel.
// ---------------------------------------------------------------------------
__global__ __launch_bounds__(256, 2) void attn_inc_kernel(
    const float* __restrict__ Q, const float* __restrict__ Kp, const float* __restrict__ Vp,
    const int* __restrict__ idxp, const float* __restrict__ maskp,
    float* __restrict__ O, int M) {
    __shared__ float Kt[32][65];
    __shared__ float Vt[32][65];
    __shared__ float Qs[32][36];
    __shared__ float Ps[4][64];

    int b = blockIdx.z, h = blockIdx.y;
    int tid = threadIdx.x;
    int lane = tid & 63, wid = tid >> 6;
    int mblk = blockIdx.x * 32;
    int m0 = mblk + wid * 8;

    int kh = lane >> 5;
    int dv = lane & 31;

    {
        int r = tid >> 3, c = tid & 7;
        float4 qv = *(const float4*)(Q + ((size_t)b * M + mblk + r) * Dd + (size_t)h * DHh + c * 4);
        *(float4*)&Qs[r][c * 4] = qv;
    }

    float acc[8], lpart[8], mrun[8];
#pragma unroll
    for (int qi = 0; qi < 8; ++qi) { acc[qi] = 0.f; lpart[qi] = 0.f; mrun[qi] = -INFINITY; }

    for (int n0 = 0; n0 < Nn; n0 += 64) {
        __syncthreads();
        {
            int k = tid >> 2, q4 = tid & 3;
            size_t gk = ((size_t)b * Nn + n0 + k) * Dd + (size_t)h * DHh;
            const float4* kp = (const float4*)(Kp + gk) + q4 * 2;
            const float4* vp = (const float4*)(Vp + gk) + q4 * 2;
            float4 k0 = kp[0], k1 = kp[1];
            float4 v0 = vp[0], v1 = vp[1];
            int d0 = q4 * 8;
            Kt[d0 + 0][k] = k0.x; Kt[d0 + 1][k] = k0.y; Kt[d0 + 2][k] = k0.z; Kt[d0 + 3][k] = k0.w;
            Kt[d0 + 4][k] = k1.x; Kt[d0 + 5][k] = k1.y; Kt[d0 + 6][k] = k1.z; Kt[d0 + 7][k] = k1.w;
            Vt[d0 + 0][k] = v0.x; Vt[d0 + 1][k] = v0.y; Vt[d0 + 2][k] = v0.z; Vt[d0 + 3][k] = v0.w;
            Vt[d0 + 4][k] = v1.x; Vt[d0 + 5][k] = v1.y; Vt[d0 + 6][k] = v1.z; Vt[d0 + 7][k] = v1.w;
        }
        float km = maskp[(size_t)b * Nn + n0 + lane];
        bool kok = (km != 0.0f);
        int tag = idxp[(size_t)b * Nn + n0 + lane];
        __syncthreads();

        bool anyUse = __any(kok && (unsigned)(tag - m0) < 8u);
        float minm = fminf(fminf(fminf(mrun[0], mrun[1]), fminf(mrun[2], mrun[3])),
                           fminf(fminf(mrun[4], mrun[5]), fminf(mrun[6], mrun[7])));
        if (!anyUse && minm > -5e9f) continue;

        float kreg[32], vreg[32];
#pragma unroll
        for (int j = 0; j < 32; ++j) kreg[j] = Kt[j][lane];
#pragma unroll
        for (int j = 0; j < 32; ++j) vreg[j] = Vt[dv][kh * 32 + j];

#pragma unroll
        for (int qi = 0; qi < 8; ++qi) {
            bool ok = kok && (tag == m0 + qi);
            if (!__any(ok) && mrun[qi] > -5e9f) continue;

            const float4* qrow = (const float4*)&Qs[wid * 8 + qi][0];
            float s0 = 0.f, s1 = 0.f, s2 = 0.f, s3 = 0.f;
#pragma unroll
            for (int j4 = 0; j4 < 8; ++j4) {
                float4 qv = qrow[j4];
                s0 += qv.x * kreg[j4 * 4 + 0];
                s1 += qv.y * kreg[j4 * 4 + 1];
                s2 += qv.z * kreg[j4 * 4 + 2];
                s3 += qv.w * kreg[j4 * 4 + 3];
            }
            float s = (s0 + s1) + (s2 + s3);
            s = ok ? s * SCALE_INV_SQRT_D : -1e10f;

            float cmax = s;
#pragma unroll
            for (int off = 32; off >= 1; off >>= 1)
                cmax = fmaxf(cmax, __shfl_xor(cmax, off, 64));

            if (cmax > mrun[qi]) {
                float corr = __expf(mrun[qi] - cmax);
                lpart[qi] *= corr;
                acc[qi] *= corr;
                mrun[qi] = cmax;
            }
            float p = __expf(s - mrun[qi]);
            lpart[qi] += p;
            Ps[wid][lane] = p;

            float a = acc[qi];
#pragma unroll
            for (int j4 = 0; j4 < 8; ++j4) {
                float4 pv = *(const float4*)&Ps[wid][kh * 32 + j4 * 4];
                a += pv.x * vreg[j4 * 4 + 0];
                a += pv.y * vreg[j4 * 4 + 1];
                a += pv.z * vreg[j4 * 4 + 2];
                a += pv.w * vreg[j4 * 4 + 3];
            }
            acc[qi] = a;
        }
    }

#pragma unroll
    for (int qi = 0; qi < 8; ++qi) {
        float l = lpart[qi];
#pragma unroll
        for (int off = 32; off >= 1; off >>= 1) l += __shfl_xor(l, off, 64);
        float a = acc[qi] + __shfl_xor(acc[qi], 32, 64);
        float inv = 1.0f / l;
        if (lane < 32) {
            int r = wid * 8 + qi;
            float qd = Qs[r][lane];
            O[((size_t)b * M + mblk + r) * Dd + (size_t)h * DHh + lane] = qd + a * inv;
        }
    }
}

// ---------------------------------------------------------------------------
// Obs (nmask) attention via bf16 MFMA with split-precision (hi+lo, 3 MFMAs
// per product ~ fp32 accuracy). Block = 16 q-rows of one (b,h), 4 waves.
// Two 512-key super-chunks; S[16][524] f32 scores in LDS; flash-merge via
// per-row corr between super-chunks; PV accumulates in MFMA C-regs
// (unnormalized); epilogue divides by row sum and adds the Q residual.
// Layout facts used: A/B i,j = lane%16 (k-permutation cancels since A and B
// use the same per-lane k formula); C/D row=(lane>>4)*4+reg, col=lane&15
// (HW-verified, guide §3).
// ---------------------------------------------------------------------------
#define SROW 524
__global__ __launch_bounds__(256, 2) void attn_obs_mfma_kernel(
    const float* __restrict__ Q, const float* __restrict__ Kp, const float* __restrict__ Vp,
    const float* __restrict__ maskp, float* __restrict__ O) {
    __shared__ float S[16][SROW];
    __shared__ float Op[2][16][33];
    __shared__ float okq_s[16];
    __shared__ float mrow[16], lrow[16], crow[16];

    int b = blockIdx.z, h = blockIdx.y;
    int m0 = blockIdx.x * 16;
    int tid = threadIdx.x;
    int lane = tid & 63, w = tid >> 6;
    int fr = lane & 15, fg = lane >> 4;  // fragment row/col and k-group

    if (tid < 16) {
        okq_s[tid] = maskp[(size_t)b * Nn + m0 + tid];
        mrow[tid] = -INFINITY;
        lrow[tid] = 0.0f;
    }

    // Q fragment: row fr, dims fg*8..+7 (split hi/lo)
    bf16x8 qh, ql;
    {
        const float* qp = Q + ((size_t)b * Nn + m0 + fr) * Dd + (size_t)h * DHh + fg * 8;
        float qv[8];
        *(float4*)&qv[0] = *(const float4*)qp;
        *(float4*)&qv[4] = *(const float4*)(qp + 4);
        split8(qv, qh, ql);
    }

    int khalf = w >> 1, dhalf = w & 1;
    f32x4 oacc = {0.f, 0.f, 0.f, 0.f};
    __syncthreads();

    for (int sc = 0; sc < 2; ++sc) {
        // ---- S phase: wave w computes keys [sc*512 + w*128, +128) ----
        for (int i = 0; i < 8; ++i) {
            int ktl = w * 8 + i;                  // local 16-key tile in [0,32)
            int key = sc * 512 + ktl * 16 + fr;   // this lane's key (B col)
            const float* kp = Kp + ((size_t)b * Nn + key) * Dd + (size_t)h * DHh + fg * 8;
            float kv[8];
            *(float4*)&kv[0] = *(const float4*)kp;
            *(float4*)&kv[4] = *(const float4*)(kp + 4);
            bf16x8 kh_, kl_;
            split8(kv, kh_, kl_);
            f32x4 c = {0.f, 0.f, 0.f, 0.f};
            c = __builtin_amdgcn_mfma_f32_16x16x32_bf16(qh, kh_, c, 0, 0, 0);
            c = __builtin_amdgcn_mfma_f32_16x16x32_bf16(qh, kl_, c, 0, 0, 0);
            c = __builtin_amdgcn_mfma_f32_16x16x32_bf16(ql, kh_, c, 0, 0, 0);
            float km = maskp[(size_t)b * Nn + key];
            bool kok = (km != 0.0f);
#pragma unroll
            for (int r = 0; r < 4; ++r) {
                int row = fg * 4 + r;
                bool ok = kok && (okq_s[row] != 0.0f);
                S[row][ktl * 16 + fr] = ok ? c[r] * SCALE_INV_SQRT_D : -1e10f;
            }
        }
        __syncthreads();

        // ---- softmax-lite: chunk max, merge, exp in place, sums ----
        {
            int row = tid >> 4, seg = tid & 15;  // 16 threads per row, same wave
            float* rp = &S[row][0];
            float mx = -INFINITY;
#pragma unroll 4
            for (int ii = 0; ii < 32; ++ii) mx = fmaxf(mx, rp[seg + 16 * ii]);
#pragma unroll
            for (int off = 1; off < 16; off <<= 1) mx = fmaxf(mx, __shfl_xor(mx, off, 16));
            float mold = mrow[row];
            float mnew = fmaxf(mold, mx);
            float corr = __expf(mold - mnew);  // exp(-inf)=0 on first chunk
            float lsum = 0.f;
#pragma unroll 4
            for (int ii = 0; ii < 32; ++ii) {
                float e = __expf(rp[seg + 16 * ii] - mnew);
                rp[seg + 16 * ii] = e;
                lsum += e;
            }
#pragma unroll
            for (int off = 1; off < 16; off <<= 1) lsum += __shfl_xor(lsum, off, 16);
            if (seg == 0) {
                lrow[row] = lrow[row] * corr + lsum;
                mrow[row] = mnew;
                crow[row] = corr;
            }
        }
        __syncthreads();

        // ---- PV phase: wave (khalf,dhalf): keys [khalf*256,+256), dims 16 ----
#pragma unroll
        for (int r = 0; r < 4; ++r) oacc[r] *= crow[fg * 4 + r];
        for (int i = 0; i < 8; ++i) {
            int chl = khalf * 8 + i;  // local 32-key chunk
            const float* pp = &S[fr][chl * 32 + fg * 8];
            float pv[8];
            *(float4*)&pv[0] = *(const float4*)pp;
            *(float4*)&pv[4] = *(const float4*)(pp + 4);
            bf16x8 ph, pl;
            split8(pv, ph, pl);
            int keyb = sc * 512 + chl * 32 + fg * 8;
            int d = dhalf * 16 + fr;
            float vv[8];
#pragma unroll
            for (int j = 0; j < 8; ++j)
                vv[j] = Vp[((size_t)b * Nn + keyb + j) * Dd + (size_t)h * DHh + d];
            bf16x8 vh, vl;
            split8(vv, vh, vl);
            oacc = __builtin_amdgcn_mfma_f32_16x16x32_bf16(ph, vh, oacc, 0, 0, 0);
            oacc = __builtin_amdgcn_mfma_f32_16x16x32_bf16(ph, vl, oacc, 0, 0, 0);
            oacc = __builtin_amdgcn_mfma_f32_16x16x32_bf16(pl, vh, oacc, 0, 0, 0);
        }
        __syncthreads();  // S reused by next super-chunk
    }

    // ---- write partials, combine, residual ----
#pragma unroll
    for (int r = 0; r < 4; ++r) Op[khalf][fg * 4 + r][dhalf * 16 + fr] = oacc[r];
    __syncthreads();
    for (int e = tid; e < 16 * 32; e += 256) {
        int row = e >> 5, d = e & 31;
        float val = (Op[0][row][d] + Op[1][row][d]) / lrow[row];
        size_t gi = ((size_t)b * Nn + m0 + row) * Dd + (size_t)h * DHh + d;
        O[gi] = Q[gi] + val;
    }
}

// ---------------------------------------------------------------------------
// IAA (hyperedge2hyperedge): tiny single-head attention over E=32.
// ---------------------------------------------------------------------------
__global__ void iaa_scores_kernel(const float* __restrict__ q, const float* __restrict__ k,
                                  float* __restrict__ s) {
    int t = blockIdx.x * 256 + threadIdx.x;
    if (t >= Bb * Ee * Ee) return;
    int j = t & (Ee - 1);
    int i = (t >> 5) & (Ee - 1);
    int b = t >> 10;
    const float4* qp = (const float4*)(q + ((size_t)b * Ee + i) * Dd);
    const float4* kp = (const float4*)(k + ((size_t)b * Ee + j) * Dd);
    float acc = 0.0f;
#pragma unroll
    for (int d = 0; d < 32; ++d) {
        float4 a = qp[d], c = kp[d];
        acc += a.x * c.x + a.y * c.y + a.z * c.z + a.w * c.w;
    }
    s[t] = acc * SCALE_INV_SQRT_D;
}

__global__ void iaa_softmax_kernel(float* __restrict__ s) {
    int r = blockIdx.x * 256 + threadIdx.x;
    if (r >= Bb * Ee) return;
    float* row = s + (size_t)r * Ee;
    float mx = -INFINITY;
    for (int j = 0; j < Ee; ++j) mx = fmaxf(mx, row[j]);
    float sum = 0.0f;
    for (int j = 0; j < Ee; ++j) sum += __expf(row[j] - mx);
    float inv = 1.0f / sum;
    for (int j = 0; j < Ee; ++j) row[j] = __expf(row[j] - mx) * inv;
}

__global__ void iaa_av_kernel(const float* __restrict__ s, const float* __restrict__ v,
                              float* __restrict__ o) {
    int t = blockIdx.x * 256 + threadIdx.x;
    if (t >= Bb * Ee * Dd) return;
    int d = t & (Dd - 1);
    int i = (t >> 7) & (Ee - 1);
    int b = t >> 12;
    const float* sr = s + ((size_t)b * Ee + i) * Ee;
    float acc = 0.0f;
#pragma unroll
    for (int j = 0; j < Ee; ++j) acc += sr[j] * v[((size_t)b * Ee + j) * Dd + d];
    o[t] = acc;
}

// ---------------------------------------------------------------------------
// Host-side orchestration
// ---------------------------------------------------------------------------
static inline void launch_gemm(hipStream_t st, const float* X0, const int* I0, int R0,
                               const float* X1, const int* I1, int R1, const float* X2,
                               const int* I2, int R2, const float* W, const float* bias,
                               const float* resid, float* C, int M, int K, int epi) {
    dim3 g((M + 31) / 32, 1, Bb);
    gemm_kernel<<<g, 256, 0, st>>>(X0, I0, R0, X1, I1, R1, X2, I2, R2, W, bias, resid, C, M, K,
                                   epi);
}

static inline void launch_attn_inc(hipStream_t st, const float* Q, const float* K, const float* V,
                                   const int* idxp, const float* maskp, float* O, int M) {
    dim3 g(M / 32, Hh, Bb);
    attn_inc_kernel<<<g, 256, 0, st>>>(Q, K, V, idxp, maskp, O, M);
}

static inline void launch_attn_obs(hipStream_t st, const float* Q, const float* K, const float* V,
                                   const float* maskp, float* O) {
    dim3 g(Nn / 16, Hh, Bb);
    attn_obs_mfma_kernel<<<g, 256, 0, st>>>(Q, K, V, maskp, O);
}

extern "C" void kernel_launch(void* const* d_in, const int* in_sizes, int n_in, void* d_out,
                              int out_size, void* d_ws, size_t ws_size, hipStream_t stream) {
    const float* x = (const float*)d_in[0];
    const float* mask = (const float*)d_in[1];
    const float* ymask = (const float*)d_in[2];
    const float* mark = (const float*)d_in[3];
    const float* w_obs = (const float*)d_in[4];
    const float* b_obs = (const float*)d_in[5];
    const float* w_tm = (const float*)d_in[6];
    const float* b_tm = (const float*)d_in[7];
    const float* var_w = (const float*)d_in[8];
    const float* tq_w = (const float*)d_in[9];
    const float* tq_b = (const float*)d_in[10];
    const float* tk_w = (const float*)d_in[11];
    const float* tk_b = (const float*)d_in[12];
    const float* tv_w = (const float*)d_in[13];
    const float* tv_b = (const float*)d_in[14];
    const float* to_w = (const float*)d_in[15];
    const float* to_b = (const float*)d_in[16];
    const float* vq_w = (const float*)d_in[17];
    const float* vq_b = (const float*)d_in[18];
    const float* vk_w = (const float*)d_in[19];
    const float* vk_b = (const float*)d_in[20];
    const float* vv_w = (const float*)d_in[21];
    const float* vv_b = (const float*)d_in[22];
    const float* vo_w = (const float*)d_in[23];
    const float* vo_b = (const float*)d_in[24];
    const float* sq_w = (const float*)d_in[25];
    const float* sq_b = (const float*)d_in[26];
    const float* sk_w = (const float*)d_in[27];
    const float* sk_b = (const float*)d_in[28];
    const float* sv_w = (const float*)d_in[29];
    const float* sv_b = (const float*)d_in[30];
    const float* so_w = (const float*)d_in[31];
    const float* so_b = (const float*)d_in[32];
    const float* iq_w = (const float*)d_in[33];
    const float* iq_b = (const float*)d_in[34];
    const float* ik_w = (const float*)d_in[35];
    const float* ik_b = (const float*)d_in[36];
    const float* iv_w = (const float*)d_in[37];
    const float* iv_b = (const float*)d_in[38];
    const int* vidx = (const int*)d_in[39];
    const int* tidx = (const int*)d_in[40];

    float* out = (float*)d_out;
    float* out_obs = out;
    float* out_temp = out + BND;
    float* out_var = out + BND + BLD;

    float* ws = (float*)d_ws;
    float* obs_a = ws;
    float* obs_b = obs_a + BND;
    float* qb = obs_b + BND;
    float* kb = qb + BND;
    float* vb = kb + BND;
    float* attno = vb + BND;
    float* temp_a = attno + BND;
    float* temp_b = temp_a + BLD;
    float* var_a = temp_b + BLD;
    float* var_b = var_a + BED;
    float* sbuf = var_b + BED;  // B*E*E

    enc_obs_kernel<<<(BND + 255) / 256, 256, 0, stream>>>(x, mask, ymask, w_obs, b_obs, obs_a);
    enc_temp_kernel<<<(BLD + 255) / 256, 256, 0, stream>>>(mark, w_tm, b_tm, temp_a);
    enc_var_kernel<<<(BED + 255) / 256, 256, 0, stream>>>(var_w, var_a);

    float* t_old = temp_a;
    float* v_old = var_a;
    float* o_old = obs_a;

    for (int i = 0; i < NLn; ++i) {
        int last = (i == NLn - 1);
        float* t_new = last ? out_temp : temp_b;
        float* v_new = (v_old == var_a) ? var_b : var_a;
        float* o_new = last ? out_obs : obs_b;

        const float* tqW = tq_w + (size_t)i * Dd * Dd;
        const float* tkW = tk_w + (size_t)i * 2 * Dd * Dd;
        const float* tvW = tv_w + (size_t)i * 2 * Dd * Dd;
        const float* toW = to_w + (size_t)i * Dd * Dd;
        const float* vqW = vq_w + (size_t)i * Dd * Dd;
        const float* vkW = vk_w + (size_t)i * 2 * Dd * Dd;
        const float* vvW = vv_w + (size_t)i * 2 * Dd * Dd;
        const float* voW = vo_w + (size_t)i * Dd * Dd;
        const float* sqW = sq_w + (size_t)i * Dd * Dd;
        const float* skW = sk_w + (size_t)i * 3 * Dd * Dd;
        const float* svW = sv_w + (size_t)i * 3 * Dd * Dd;
        const float* soW = so_w + (size_t)i * Dd * Dd;

        // ---- temporal MAB: Q=temp_he(old), K=[var_g(old), obs] ----
        launch_gemm(stream, t_old, nullptr, Ll, nullptr, nullptr, 0, nullptr, nullptr, 0, tqW,
                    tq_b + i * Dd, nullptr, qb, Ll, Dd, 0);
        launch_gemm(stream, v_old, vidx, Ee, o_old, nullptr, Nn, nullptr, nullptr, 0, tkW,
                    tk_b + i * Dd, nullptr, kb, Nn, 2 * Dd, 0);
        launch_gemm(stream, v_old, vidx, Ee, o_old, nullptr, Nn, nullptr, nullptr, 0, tvW,
                    tv_b + i * Dd, nullptr, vb, Nn, 2 * Dd, 0);
        launch_attn_inc(stream, qb, kb, vb, tidx, mask, attno, Ll);
        launch_gemm(stream, attno, nullptr, Ll, nullptr, nullptr, 0, nullptr, nullptr, 0, toW,
                    to_b + i * Dd, attno, t_new, Ll, Dd, 1);

        // ---- variable MAB: Q=var_he(old), K=[temp_g(old), obs] ----
        launch_gemm(stream, v_old, nullptr, Ee, nullptr, nullptr, 0, nullptr, nullptr, 0, vqW,
                    vq_b + i * Dd, nullptr, qb, Ee, Dd, 0);
        launch_gemm(stream, t_old, tidx, Ll, o_old, nullptr, Nn, nullptr, nullptr, 0, vkW,
                    vk_b + i * Dd, nullptr, kb, Nn, 2 * Dd, 0);
        launch_gemm(stream, t_old, tidx, Ll, o_old, nullptr, Nn, nullptr, nullptr, 0, vvW,
                    vv_b + i * Dd, nullptr, vb, Nn, 2 * Dd, 0);
        launch_attn_inc(stream, qb, kb, vb, vidx, mask, attno, Ee);
        launch_gemm(stream, attno, nullptr, Ee, nullptr, nullptr, 0, nullptr, nullptr, 0, voW,
                    vo_b + i * Dd, attno, v_new, Ee, Dd, 1);

        // ---- obs MAB: Q=obs(old), K=[temp_g(new), var_g(new), obs(old)] ----
        launch_gemm(stream, o_old, nullptr, Nn, nullptr, nullptr, 0, nullptr, nullptr, 0, sqW,
                    sq_b + i * Dd, nullptr, qb, Nn, Dd, 0);
        launch_gemm(stream, t_new, tidx, Ll, v_new, vidx, Ee, o_old, nullptr, Nn, skW,
                    sk_b + i * Dd, nullptr, kb, Nn, 3 * Dd, 0);
        launch_gemm(stream, t_new, tidx, Ll, v_new, vidx, Ee, o_old, nullptr, Nn, svW,
                    sv_b + i * Dd, nullptr, vb, Nn, 3 * Dd, 0);
        launch_attn_obs(stream, qb, kb, vb, mask, attno);
        launch_gemm(stream, attno, nullptr, Nn, nullptr, nullptr, 0, nullptr, nullptr, 0, soW,
                    so_b + i * Dd, attno, o_new, Nn, Dd, 2);

        t_old = t_new;
        v_old = v_new;
        o_old = o_new;
    }

    // ---- IAA on var_he (last layer) ----
    launch_gemm(stream, v_old, nullptr, Ee, nullptr, nullptr, 0, nullptr, nullptr, 0, iq_w, iq_b,
                nullptr, qb, Ee, Dd, 0);
    launch_gemm(stream, v_old, nullptr, Ee, nullptr, nullptr, 0, nullptr, nullptr, 0, ik_w, ik_b,
                nullptr, kb, Ee, Dd, 0);
    launch_gemm(stream, v_old, nullptr, Ee, nullptr, nullptr, 0, nullptr, nullptr, 0, iv_w, iv_b,
                nullptr, vb, Ee, Dd, 0);
    iaa_scores_kernel<<<(Bb * Ee * Ee + 255) / 256, 256, 0, stream>>>(qb, kb, sbuf);
    iaa_softmax_kernel<<<(Bb * Ee + 255) / 256, 256, 0, stream>>>(sbuf);
    iaa_av_kernel<<<(Bb * Ee * Dd + 255) / 256, 256, 0, stream>>>(sbuf, vb, out_var);
}